// Round 1
// baseline (1804.866 us; speedup 1.0000x reference)
//
#include <hip/hip_runtime.h>
#include <hip/hip_bf16.h>
#include <cstdint>

// ---------------------------------------------------------------------------
// Problem geometry (fixed):
//  x: (2,128,248,248)  sp: (2,128,62,62)
//  p1=32 s1=24 (kv windows, 10x10=100), p2=8 s2=6 (q windows, 10x10=100)
//  HEADS=4, hd=32. Output: (2,128,62,62) fp32.
// ---------------------------------------------------------------------------

#define HS 62
#define HX 248

// ---------------------------------------------------------------------------
// Depthwise 3x3, pad 1, optional bias, optional residual (y = x + conv)
// ---------------------------------------------------------------------------
__global__ void dwconv3_kernel(const float* __restrict__ x, const float* __restrict__ w,
                               const float* __restrict__ bias, float* __restrict__ y,
                               int C, int H, int W, int total, int residual) {
  int i = blockIdx.x * 256 + threadIdx.x;
  if (i >= total) return;
  int wx = i % W;
  int t = i / W;
  int hy = t % H;
  int bc = t / H;          // b*C + c
  int c = bc % C;
  const float* xb = x + (size_t)bc * H * W;
  const float* wc = w + c * 9;
  float s = bias ? bias[c] : 0.0f;
  for (int di = -1; di <= 1; di++) {
    int h2 = hy + di;
    if (h2 < 0 || h2 >= H) continue;
    for (int dj = -1; dj <= 1; dj++) {
      int w2 = wx + dj;
      if (w2 < 0 || w2 >= W) continue;
      s += xb[(size_t)h2 * W + w2] * wc[(di + 1) * 3 + (dj + 1)];
    }
  }
  if (residual) s += xb[(size_t)hy * W + wx];
  y[i] = s;
}

// ---------------------------------------------------------------------------
// 1x1 conv as GEMM: y[b,o,p] = sum_c x[b,c,p] * w[o,c].  K=128 fixed.
// Block: 256 threads = 4 output-groups x 64 pixels; x-tile staged in LDS.
// ---------------------------------------------------------------------------
template <int O>
__global__ __launch_bounds__(256) void conv1_kernel(const float* __restrict__ x,
                                                    const float* __restrict__ w,
                                                    float* __restrict__ y, int HW) {
  constexpr int K = 128;
  __shared__ float xs[K * 64];
  int b = blockIdx.y;
  int p0 = blockIdx.x * 64;
  const float* xb = x + (size_t)b * K * HW;
  for (int e = threadIdx.x; e < K * 64; e += 256) {
    int c = e >> 6, pp = e & 63;
    int p = p0 + pp;
    xs[e] = (p < HW) ? xb[(size_t)c * HW + p] : 0.0f;
  }
  __syncthreads();
  int pp = threadIdx.x & 63;
  int og = threadIdx.x >> 6;  // 0..3 (one wave per group)
  constexpr int OS = O / 4;
  float acc[OS];
#pragma unroll
  for (int j = 0; j < OS; j++) acc[j] = 0.0f;
  const float* wg = w + (size_t)og * OS * K;
  for (int k = 0; k < K; k++) {
    float xv = xs[k * 64 + pp];
#pragma unroll
    for (int j = 0; j < OS; j++) acc[j] += wg[j * K + k] * xv;
  }
  int p = p0 + pp;
  if (p < HW) {
    float* yb = y + (size_t)b * O * HW + (size_t)og * OS * HW + p;
#pragma unroll
    for (int j = 0; j < OS; j++) yb[(size_t)j * HW] = acc[j];
  }
}

// ---------------------------------------------------------------------------
// Windowed attention. One wave per (window n, head h, batch b).
// lane = query position (8x8=64).  K/V: 1024 positions x 32 ch, staged in LDS
// in chunks of 64 keys, [ch][kk] layout so score/PV loops do float4 LDS reads.
// Online softmax (chunk-of-4 rescale).
// out: (2,100,128,8,8)
// ---------------------------------------------------------------------------
__global__ __launch_bounds__(64) void attn_kernel(const float* __restrict__ q,
                                                  const float* __restrict__ kv,
                                                  float* __restrict__ o) {
  int n = blockIdx.x;   // 0..99
  int h = blockIdx.y;   // 0..3
  int b = blockIdx.z;   // 0..1
  int wi = n / 10, wj = n % 10;
  int lane = threadIdx.x;  // query pos
  int qi = lane >> 3, qj = lane & 7;
  const float scale = 0.17677669529663688f;  // 32^-0.5

  float qr[32];
  const float* qbase = q + ((size_t)(b * 128 + h * 32)) * (HS * HS) + (6 * wi + qi) * HS + (6 * wj + qj);
#pragma unroll
  for (int ch = 0; ch < 32; ch++) qr[ch] = qbase[(size_t)ch * HS * HS] * scale;

  __shared__ __align__(16) float Ks[32 * 64];
  __shared__ __align__(16) float Vs[32 * 64];

  float m = -1e30f, l = 0.0f;
  float acc[32];
#pragma unroll
  for (int ch = 0; ch < 32; ch++) acc[ch] = 0.0f;

  const size_t HW = (size_t)HX * HX;
  const float* kbase = kv + ((size_t)(b * 256 + h * 32)) * HW;
  const float* vbase = kv + ((size_t)(b * 256 + 128 + h * 32)) * HW;
  int y0 = 24 * wi, x0 = 24 * wj;

  for (int kc = 0; kc < 1024; kc += 64) {
    __syncthreads();
    {
      int kpos = kc + lane;
      int yy = y0 + (kpos >> 5);
      int xx = x0 + (kpos & 31);
      size_t off = (size_t)yy * HX + xx;
#pragma unroll
      for (int ch = 0; ch < 32; ch++) {
        Ks[ch * 64 + lane] = kbase[ch * HW + off];
        Vs[ch * 64 + lane] = vbase[ch * HW + off];
      }
    }
    __syncthreads();
    for (int g = 0; g < 64; g += 4) {
      float s0 = 0.f, s1 = 0.f, s2 = 0.f, s3 = 0.f;
#pragma unroll
      for (int ch = 0; ch < 32; ch++) {
        float4 kvv = *(const float4*)&Ks[ch * 64 + g];
        float qv = qr[ch];
        s0 += qv * kvv.x; s1 += qv * kvv.y; s2 += qv * kvv.z; s3 += qv * kvv.w;
      }
      float cm = fmaxf(fmaxf(s0, s1), fmaxf(s2, s3));
      float mn = fmaxf(m, cm);
      float alpha = __expf(m - mn);
      m = mn;
      float p0 = __expf(s0 - mn), p1 = __expf(s1 - mn);
      float p2 = __expf(s2 - mn), p3 = __expf(s3 - mn);
      l = l * alpha + (p0 + p1 + p2 + p3);
#pragma unroll
      for (int ch = 0; ch < 32; ch++) {
        float4 vv = *(const float4*)&Vs[ch * 64 + g];
        acc[ch] = acc[ch] * alpha + p0 * vv.x + p1 * vv.y + p2 * vv.z + p3 * vv.w;
      }
    }
  }
  float inv_l = 1.0f / l;
  float* obase = o + (((size_t)(b * 100 + n)) * 128 + h * 32) * 64 + lane;
#pragma unroll
  for (int ch = 0; ch < 32; ch++) obase[ch * 64] = acc[ch] * inv_l;
}

// ---------------------------------------------------------------------------
// Reverse: scatter-average overlapping 8x8 windows (step 6) into (2,128,62,62)
// win: (2,100,128,8,8)
// ---------------------------------------------------------------------------
__global__ void reverse_kernel(const float* __restrict__ win, float* __restrict__ out) {
  int i = blockIdx.x * 256 + threadIdx.x;
  const int total = 2 * 128 * HS * HS;
  if (i >= total) return;
  int x = i % HS;
  int t = i / HS;
  int y = t % HS;
  t /= HS;
  int c = t % 128;
  int b = t / 128;
  int wi0 = (y >= 7) ? (y - 2) / 6 : 0;
  int wi1 = min(9, y / 6);
  int wj0 = (x >= 7) ? (x - 2) / 6 : 0;
  int wj1 = min(9, x / 6);
  float s = 0.0f;
  for (int wi = wi0; wi <= wi1; wi++)
    for (int wj = wj0; wj <= wj1; wj++) {
      int di = y - 6 * wi, dj = x - 6 * wj;
      s += win[(((size_t)(b * 100 + wi * 10 + wj)) * 128 + c) * 64 + di * 8 + dj];
    }
  float cnt = (float)((wi1 - wi0 + 1) * (wj1 - wj0 + 1));
  out[i] = s / cnt;
}

// ---------------------------------------------------------------------------
extern "C" void kernel_launch(void* const* d_in, const int* in_sizes, int n_in,
                              void* d_out, int out_size, void* d_ws, size_t ws_size,
                              hipStream_t stream) {
  const float* x      = (const float*)d_in[0];
  const float* sp     = (const float*)d_in[1];
  const float* w_pos  = (const float*)d_in[2];
  const float* b_pos  = (const float*)d_in[3];
  const float* w_q    = (const float*)d_in[4];
  const float* w_qdw  = (const float*)d_in[5];
  const float* w_kv   = (const float*)d_in[6];
  const float* w_kvdw = (const float*)d_in[7];
  const float* w_out  = (const float*)d_in[8];
  float* out = (float*)d_out;

  const size_t N_x   = (size_t)2 * 128 * HX * HX;   // 15,745,024
  const size_t N_t   = (size_t)2 * 256 * HX * HX;   // 31,490,048
  const size_t N_s   = (size_t)2 * 128 * HS * HS;   //    984,064
  const size_t N_att = (size_t)2 * 100 * 128 * 64;  //  1,638,400

  float* ws  = (float*)d_ws;
  float* kvb = ws;            // [0, N_t): kv (final); first N_x floats alias xp
  float* xp  = ws;            // alias — dead before kvb is written
  float* tkv = ws + N_t;      // [N_t, 2N_t): conv1(xp, w_kv) pre-dwconv
  float* spp = ws + 2 * N_t;
  float* tq  = spp + N_s;
  float* qb  = tq + N_s;
  float* att = tkv;           // alias — tkv dead after kv dwconv
  float* rev = tkv + N_att;
  (void)ws_size; (void)in_sizes; (void)n_in; (void)out_size;

  // 1. xp = x + dwconv3(x, w_pos, b_pos)
  {
    int total = (int)N_x;
    dwconv3_kernel<<<(total + 255) / 256, 256, 0, stream>>>(x, w_pos, b_pos, xp, 128, HX, HX, total, 1);
  }
  // 2. spp = sp + dwconv3(sp, w_pos, b_pos)
  {
    int total = (int)N_s;
    dwconv3_kernel<<<(total + 255) / 256, 256, 0, stream>>>(sp, w_pos, b_pos, spp, 128, HS, HS, total, 1);
  }
  // 3. tq = conv1(spp, w_q)
  {
    int HW = HS * HS;
    dim3 grid((HW + 63) / 64, 2);
    conv1_kernel<128><<<grid, 256, 0, stream>>>(spp, w_q, tq, HW);
  }
  // 4. qb = dwconv3(tq, w_qdw)
  {
    int total = (int)N_s;
    dwconv3_kernel<<<(total + 255) / 256, 256, 0, stream>>>(tq, w_qdw, nullptr, qb, 128, HS, HS, total, 0);
  }
  // 5. tkv = conv1(xp, w_kv)   (O=256)
  {
    int HW = HX * HX;
    dim3 grid((HW + 63) / 64, 2);
    conv1_kernel<256><<<grid, 256, 0, stream>>>(xp, w_kv, tkv, HW);
  }
  // 6. kvb = dwconv3(tkv, w_kvdw)   (overwrites xp region; xp dead)
  {
    int total = (int)N_t;
    dwconv3_kernel<<<(total + 255) / 256, 256, 0, stream>>>(tkv, w_kvdw, nullptr, kvb, 256, HX, HX, total, 0);
  }
  // 7. attention -> att (2,100,128,8,8)   (att aliases tkv; tkv dead)
  {
    dim3 grid(100, 4, 2);
    attn_kernel<<<grid, 64, 0, stream>>>(qb, kvb, att);
  }
  // 8. rev = reverse(att)
  {
    int total = (int)N_s;
    reverse_kernel<<<(total + 255) / 256, 256, 0, stream>>>(att, rev);
  }
  // 9. out = conv1(rev, w_out)
  {
    int HW = HS * HS;
    dim3 grid((HW + 63) / 64, 2);
    conv1_kernel<128><<<grid, 256, 0, stream>>>(rev, w_out, out, HW);
  }
}

// Round 2
// 680.483 us; speedup vs baseline: 2.6523x; 2.6523x over previous
//
#include <hip/hip_runtime.h>
#include <hip/hip_bf16.h>
#include <cstdint>

// ---------------------------------------------------------------------------
// Problem geometry (fixed):
//  x: (2,128,248,248)  sp: (2,128,62,62)
//  p1=32 s1=24 (kv windows, 10x10=100), p2=8 s2=6 (q windows, 10x10=100)
//  HEADS=4, hd=32. Output: (2,128,62,62) fp32.
// ---------------------------------------------------------------------------

#define HS 62
#define HX 248

// ---------------------------------------------------------------------------
// Depthwise 3x3, pad 1, optional bias, optional residual. Scalar version
// (used for the small 62x62 tensors where W%4 != 0).
// ---------------------------------------------------------------------------
__global__ void dwconv3_kernel(const float* __restrict__ x, const float* __restrict__ w,
                               const float* __restrict__ bias, float* __restrict__ y,
                               int C, int H, int W, int total, int residual) {
  int i = blockIdx.x * 256 + threadIdx.x;
  if (i >= total) return;
  int wx = i % W;
  int t = i / W;
  int hy = t % H;
  int bc = t / H;          // b*C + c
  int c = bc % C;
  const float* xb = x + (size_t)bc * H * W;
  const float* wc = w + c * 9;
  float s = bias ? bias[c] : 0.0f;
  for (int di = -1; di <= 1; di++) {
    int h2 = hy + di;
    if (h2 < 0 || h2 >= H) continue;
    for (int dj = -1; dj <= 1; dj++) {
      int w2 = wx + dj;
      if (w2 < 0 || w2 >= W) continue;
      s += xb[(size_t)h2 * W + w2] * wc[(di + 1) * 3 + (dj + 1)];
    }
  }
  if (residual) s += xb[(size_t)hy * W + wx];
  y[i] = s;
}

// ---------------------------------------------------------------------------
// Depthwise 3x3 vectorized: each thread computes 4 consecutive pixels.
// Requires W % 4 == 0 (W=248 here).
// ---------------------------------------------------------------------------
__global__ void dwconv4_kernel(const float* __restrict__ x, const float* __restrict__ w,
                               const float* __restrict__ bias, float* __restrict__ y,
                               int C, int H, int W, int total4, int residual) {
  int i = blockIdx.x * 256 + threadIdx.x;
  if (i >= total4) return;
  int W4 = W >> 2;
  int wq = (i % W4) * 4;
  int t = i / W4;
  int hy = t % H;
  int bc = t / H;
  int c = bc % C;
  const float* xb = x + (size_t)bc * H * W;
  const float* wc = w + c * 9;
  float bv = bias ? bias[c] : 0.0f;
  float s0 = bv, s1 = bv, s2 = bv, s3 = bv;
  for (int di = -1; di <= 1; di++) {
    int h2 = hy + di;
    if (h2 < 0 || h2 >= H) continue;
    const float* row = xb + (size_t)h2 * W + wq;
    float4 cv = *(const float4*)row;
    float lf = (wq > 0) ? row[-1] : 0.0f;
    float rt = (wq + 4 < W) ? row[4] : 0.0f;
    float w0 = wc[(di + 1) * 3 + 0];
    float w1 = wc[(di + 1) * 3 + 1];
    float w2 = wc[(di + 1) * 3 + 2];
    s0 += w0 * lf   + w1 * cv.x + w2 * cv.y;
    s1 += w0 * cv.x + w1 * cv.y + w2 * cv.z;
    s2 += w0 * cv.y + w1 * cv.z + w2 * cv.w;
    s3 += w0 * cv.z + w1 * cv.w + w2 * rt;
  }
  if (residual) {
    float4 cc = *(const float4*)(xb + (size_t)hy * W + wq);
    s0 += cc.x; s1 += cc.y; s2 += cc.z; s3 += cc.w;
  }
  *(float4*)(y + (size_t)bc * H * W + (size_t)hy * W + wq) = make_float4(s0, s1, s2, s3);
}

// ---------------------------------------------------------------------------
// 1x1 conv as tiled SGEMM: y[b,o,p] = sum_c x[b,c,p] * w[o,c].  K=128.
// Block: 256 threads -> 64 out-ch x 64 pixels, each thread 4x4 micro-tile.
// LDS tiles in [k][.] layout so inner loop is two ds_read_b128 + 16 FMA.
// ---------------------------------------------------------------------------
template <int O>
__global__ __launch_bounds__(256) void conv1_kernel(const float* __restrict__ x,
                                                    const float* __restrict__ w,
                                                    float* __restrict__ y, int HW) {
  constexpr int K = 128;
  constexpr int BK = 32;
  __shared__ __align__(16) float ws_s[BK][64];  // [k][o]
  __shared__ __align__(16) float xs_s[BK][64];  // [k][p]
  int b = blockIdx.z;
  int o0 = blockIdx.y * 64;
  int p0 = blockIdx.x * 64;
  const float* xb = x + (size_t)b * K * HW;
  int tx = threadIdx.x & 15;   // pixel group
  int ty = threadIdx.x >> 4;   // out-ch group
  float acc[4][4] = {};
  // loader indices
  int lo = threadIdx.x >> 2;         // 0..63 : output row for w-load
  int lk = (threadIdx.x & 3) * 8;    // k-offset for w-load
  int lc = threadIdx.x >> 3;         // 0..31 : channel for x-load
  int lp = (threadIdx.x & 7) * 8;    // pixel offset for x-load

  for (int k0 = 0; k0 < K; k0 += BK) {
    __syncthreads();
    {  // w tile (transpose into [k][o])
      const float* wp = w + (size_t)(o0 + lo) * K + k0 + lk;
      float4 a = *(const float4*)wp;
      float4 bq = *(const float4*)(wp + 4);
      ws_s[lk + 0][lo] = a.x;  ws_s[lk + 1][lo] = a.y;
      ws_s[lk + 2][lo] = a.z;  ws_s[lk + 3][lo] = a.w;
      ws_s[lk + 4][lo] = bq.x; ws_s[lk + 5][lo] = bq.y;
      ws_s[lk + 6][lo] = bq.z; ws_s[lk + 7][lo] = bq.w;
    }
    {  // x tile (already [k][p] in memory)
      int p = p0 + lp;
      const float* xp = xb + (size_t)(k0 + lc) * HW;
      float4 a, bq;
      if (p + 7 < HW) {
        a = *(const float4*)(xp + p);
        bq = *(const float4*)(xp + p + 4);
      } else {
        float tv[8];
#pragma unroll
        for (int j = 0; j < 8; j++) tv[j] = (p + j < HW) ? xp[p + j] : 0.0f;
        a = make_float4(tv[0], tv[1], tv[2], tv[3]);
        bq = make_float4(tv[4], tv[5], tv[6], tv[7]);
      }
      *(float4*)&xs_s[lc][lp] = a;
      *(float4*)&xs_s[lc][lp + 4] = bq;
    }
    __syncthreads();
#pragma unroll
    for (int k = 0; k < BK; k++) {
      float4 wv = *(const float4*)&ws_s[k][ty * 4];
      float4 xv = *(const float4*)&xs_s[k][tx * 4];
      acc[0][0] += wv.x * xv.x; acc[0][1] += wv.x * xv.y; acc[0][2] += wv.x * xv.z; acc[0][3] += wv.x * xv.w;
      acc[1][0] += wv.y * xv.x; acc[1][1] += wv.y * xv.y; acc[1][2] += wv.y * xv.z; acc[1][3] += wv.y * xv.w;
      acc[2][0] += wv.z * xv.x; acc[2][1] += wv.z * xv.y; acc[2][2] += wv.z * xv.z; acc[2][3] += wv.z * xv.w;
      acc[3][0] += wv.w * xv.x; acc[3][1] += wv.w * xv.y; acc[3][2] += wv.w * xv.z; acc[3][3] += wv.w * xv.w;
    }
  }
  int p = p0 + tx * 4;
  float* yb = y + (size_t)b * O * HW + (size_t)(o0 + ty * 4) * HW;
#pragma unroll
  for (int j = 0; j < 4; j++) {
    float* yr = yb + (size_t)j * HW + p;
    if (p + 3 < HW) {
      *(float4*)yr = make_float4(acc[j][0], acc[j][1], acc[j][2], acc[j][3]);
    } else {
#pragma unroll
      for (int e = 0; e < 4; e++) if (p + e < HW) yr[e] = acc[j][e];
    }
  }
}

// ---------------------------------------------------------------------------
// Windowed attention, 4 waves per block. Each wave owns 256 keys and a
// private LDS K/V buffer (no barriers in the main loop); flash-style merge
// of (m, l, acc) across waves at the end.
// out: (2,100,128,8,8)
// ---------------------------------------------------------------------------
__global__ __launch_bounds__(256) void attn_kernel(const float* __restrict__ q,
                                                   const float* __restrict__ kv,
                                                   float* __restrict__ o) {
  int n = blockIdx.x;   // 0..99
  int h = blockIdx.y;   // 0..3
  int b = blockIdx.z;   // 0..1
  int wi = n / 10, wj = n % 10;
  int wave = threadIdx.x >> 6;
  int lane = threadIdx.x & 63;  // query position
  int qi = lane >> 3, qj = lane & 7;
  const float scale = 0.17677669529663688f;  // 32^-0.5

  __shared__ __align__(16) float Ks[4 * 2048];
  __shared__ __align__(16) float Vs[4 * 2048];
  float* Kw = Ks + wave * 2048;
  float* Vw = Vs + wave * 2048;

  float qr[32];
  const float* qbase = q + ((size_t)(b * 128 + h * 32)) * (HS * HS) + (6 * wi + qi) * HS + (6 * wj + qj);
#pragma unroll
  for (int ch = 0; ch < 32; ch++) qr[ch] = qbase[(size_t)ch * HS * HS] * scale;

  float m = -1e30f, l = 0.0f;
  float acc[32];
#pragma unroll
  for (int ch = 0; ch < 32; ch++) acc[ch] = 0.0f;

  const size_t HW = (size_t)HX * HX;
  const float* kbase = kv + ((size_t)(b * 256 + h * 32)) * HW;
  const float* vbase = kbase + (size_t)128 * HW;
  int y0 = 24 * wi, x0 = 24 * wj;

  for (int kc = wave * 256; kc < wave * 256 + 256; kc += 64) {
    {  // stage 64 keys into this wave's private buffers (wave-coherent, no barrier)
      int kpos = kc + lane;
      int yy = y0 + (kpos >> 5);
      int xx = x0 + (kpos & 31);
      size_t off = (size_t)yy * HX + xx;
#pragma unroll
      for (int ch = 0; ch < 32; ch++) {
        Kw[ch * 64 + lane] = kbase[ch * HW + off];
        Vw[ch * 64 + lane] = vbase[ch * HW + off];
      }
    }
    for (int g = 0; g < 64; g += 4) {
      float s0 = 0.f, s1 = 0.f, s2 = 0.f, s3 = 0.f;
#pragma unroll
      for (int ch = 0; ch < 32; ch++) {
        float4 kvv = *(const float4*)&Kw[ch * 64 + g];
        float qv = qr[ch];
        s0 += qv * kvv.x; s1 += qv * kvv.y; s2 += qv * kvv.z; s3 += qv * kvv.w;
      }
      float cm = fmaxf(fmaxf(s0, s1), fmaxf(s2, s3));
      float mn = fmaxf(m, cm);
      float alpha = __expf(m - mn);
      m = mn;
      float p0 = __expf(s0 - mn), p1 = __expf(s1 - mn);
      float p2 = __expf(s2 - mn), p3 = __expf(s3 - mn);
      l = l * alpha + (p0 + p1 + p2 + p3);
#pragma unroll
      for (int ch = 0; ch < 32; ch++) {
        float4 vv = *(const float4*)&Vw[ch * 64 + g];
        acc[ch] = acc[ch] * alpha + p0 * vv.x + p1 * vv.y + p2 * vv.z + p3 * vv.w;
      }
    }
  }

  // ----- merge the 4 waves' partial (m, l, acc) -----
  __syncthreads();           // all waves done with K/V buffers
  float* accs = Ks;          // [w*32+ch][64]  (4*32*64 = 8192 floats)
  float* ms = Vs;            // [w*64+lane]
  float* ls = Vs + 256;
  ms[wave * 64 + lane] = m;
  ls[wave * 64 + lane] = l;
#pragma unroll
  for (int ch = 0; ch < 32; ch++) accs[(wave * 32 + ch) * 64 + lane] = acc[ch];
  __syncthreads();

  float m0 = ms[lane], m1 = ms[64 + lane], m2 = ms[128 + lane], m3 = ms[192 + lane];
  float mm = fmaxf(fmaxf(m0, m1), fmaxf(m2, m3));
  float e0 = __expf(m0 - mm), e1 = __expf(m1 - mm);
  float e2 = __expf(m2 - mm), e3 = __expf(m3 - mm);
  float lsum = ls[lane] * e0 + ls[64 + lane] * e1 + ls[128 + lane] * e2 + ls[192 + lane] * e3;
  float inv = 1.0f / lsum;
  float* obase = o + (((size_t)(b * 100 + n)) * 128 + h * 32) * 64 + lane;
  for (int ch = wave * 8; ch < wave * 8 + 8; ch++) {
    float s = accs[(0 * 32 + ch) * 64 + lane] * e0 + accs[(1 * 32 + ch) * 64 + lane] * e1 +
              accs[(2 * 32 + ch) * 64 + lane] * e2 + accs[(3 * 32 + ch) * 64 + lane] * e3;
    obase[ch * 64] = s * inv;
  }
}

// ---------------------------------------------------------------------------
// Reverse: scatter-average overlapping 8x8 windows (step 6) into (2,128,62,62)
// win: (2,100,128,8,8)
// ---------------------------------------------------------------------------
__global__ void reverse_kernel(const float* __restrict__ win, float* __restrict__ out) {
  int i = blockIdx.x * 256 + threadIdx.x;
  const int total = 2 * 128 * HS * HS;
  if (i >= total) return;
  int x = i % HS;
  int t = i / HS;
  int y = t % HS;
  t /= HS;
  int c = t % 128;
  int b = t / 128;
  int wi0 = (y >= 7) ? (y - 2) / 6 : 0;
  int wi1 = min(9, y / 6);
  int wj0 = (x >= 7) ? (x - 2) / 6 : 0;
  int wj1 = min(9, x / 6);
  float s = 0.0f;
  for (int wi = wi0; wi <= wi1; wi++)
    for (int wj = wj0; wj <= wj1; wj++) {
      int di = y - 6 * wi, dj = x - 6 * wj;
      s += win[(((size_t)(b * 100 + wi * 10 + wj)) * 128 + c) * 64 + di * 8 + dj];
    }
  float cnt = (float)((wi1 - wi0 + 1) * (wj1 - wj0 + 1));
  out[i] = s / cnt;
}

// ---------------------------------------------------------------------------
extern "C" void kernel_launch(void* const* d_in, const int* in_sizes, int n_in,
                              void* d_out, int out_size, void* d_ws, size_t ws_size,
                              hipStream_t stream) {
  const float* x      = (const float*)d_in[0];
  const float* sp     = (const float*)d_in[1];
  const float* w_pos  = (const float*)d_in[2];
  const float* b_pos  = (const float*)d_in[3];
  const float* w_q    = (const float*)d_in[4];
  const float* w_qdw  = (const float*)d_in[5];
  const float* w_kv   = (const float*)d_in[6];
  const float* w_kvdw = (const float*)d_in[7];
  const float* w_out  = (const float*)d_in[8];
  float* out = (float*)d_out;

  const size_t N_x   = (size_t)2 * 128 * HX * HX;   // 15,745,024
  const size_t N_t   = (size_t)2 * 256 * HX * HX;   // 31,490,048
  const size_t N_s   = (size_t)2 * 128 * HS * HS;   //    984,064
  const size_t N_att = (size_t)2 * 100 * 128 * 64;  //  1,638,400

  float* ws  = (float*)d_ws;
  float* kvb = ws;            // [0, N_t): kv (final); first N_x floats alias xp
  float* xp  = ws;            // alias — dead before kvb is written
  float* tkv = ws + N_t;      // [N_t, 2N_t): conv1(xp, w_kv) pre-dwconv
  float* spp = ws + 2 * N_t;
  float* tq  = spp + N_s;
  float* qb  = tq + N_s;
  float* att = tkv;           // alias — tkv dead after kv dwconv
  float* rev = tkv + N_att;
  (void)ws_size; (void)in_sizes; (void)n_in; (void)out_size;

  // 1. xp = x + dwconv3(x, w_pos, b_pos)
  {
    int total4 = (int)(N_x / 4);
    dwconv4_kernel<<<(total4 + 255) / 256, 256, 0, stream>>>(x, w_pos, b_pos, xp, 128, HX, HX, total4, 1);
  }
  // 2. spp = sp + dwconv3(sp, w_pos, b_pos)
  {
    int total = (int)N_s;
    dwconv3_kernel<<<(total + 255) / 256, 256, 0, stream>>>(sp, w_pos, b_pos, spp, 128, HS, HS, total, 1);
  }
  // 3. tq = conv1(spp, w_q)
  {
    int HW = HS * HS;
    dim3 grid((HW + 63) / 64, 2, 2);
    conv1_kernel<128><<<grid, 256, 0, stream>>>(spp, w_q, tq, HW);
  }
  // 4. qb = dwconv3(tq, w_qdw)
  {
    int total = (int)N_s;
    dwconv3_kernel<<<(total + 255) / 256, 256, 0, stream>>>(tq, w_qdw, nullptr, qb, 128, HS, HS, total, 0);
  }
  // 5. tkv = conv1(xp, w_kv)   (O=256)
  {
    int HW = HX * HX;
    dim3 grid((HW + 63) / 64, 4, 2);
    conv1_kernel<256><<<grid, 256, 0, stream>>>(xp, w_kv, tkv, HW);
  }
  // 6. kvb = dwconv3(tkv, w_kvdw)   (overwrites xp region; xp dead)
  {
    int total4 = (int)(N_t / 4);
    dwconv4_kernel<<<(total4 + 255) / 256, 256, 0, stream>>>(tkv, w_kvdw, nullptr, kvb, 256, HX, HX, total4, 0);
  }
  // 7. attention -> att (2,100,128,8,8)   (att aliases tkv; tkv dead)
  {
    dim3 grid(100, 4, 2);
    attn_kernel<<<grid, 256, 0, stream>>>(qb, kvb, att);
  }
  // 8. rev = reverse(att)
  {
    int total = (int)N_s;
    reverse_kernel<<<(total + 255) / 256, 256, 0, stream>>>(att, rev);
  }
  // 9. out = conv1(rev, w_out)
  {
    int HW = HS * HS;
    dim3 grid((HW + 63) / 64, 2, 2);
    conv1_kernel<128><<<grid, 256, 0, stream>>>(rev, w_out, out, HW);
  }
}

// Round 3
// 557.627 us; speedup vs baseline: 3.2367x; 1.2203x over previous
//
#include <hip/hip_runtime.h>
#include <cstdint>

#define HS 62
#define HX 248
#define HXW (HX * HX)  // 61504
#define HSW (HS * HS)  // 3844

typedef __attribute__((ext_vector_type(8))) short bf16x8;
typedef __attribute__((ext_vector_type(4))) float f32x4;

static __device__ __forceinline__ unsigned short f2bf(float f) {
  uint32_t u = __builtin_bit_cast(uint32_t, f);
  u += 0x7fff + ((u >> 16) & 1);  // RNE
  return (unsigned short)(u >> 16);
}

// ---------------------------------------------------------------------------
// Depthwise 3x3 scalar (62x62 tensors), fp32 out, bias+residual.
// ---------------------------------------------------------------------------
__global__ void dwconv3_kernel(const float* __restrict__ x, const float* __restrict__ w,
                               const float* __restrict__ bias, float* __restrict__ y,
                               int C, int H, int W, int total, int residual) {
  int i = blockIdx.x * 256 + threadIdx.x;
  if (i >= total) return;
  int wx = i % W;
  int t = i / W;
  int hy = t % H;
  int bc = t / H;
  int c = bc % C;
  const float* xb = x + (size_t)bc * H * W;
  const float* wc = w + c * 9;
  float s = bias ? bias[c] : 0.0f;
  for (int di = -1; di <= 1; di++) {
    int h2 = hy + di;
    if (h2 < 0 || h2 >= H) continue;
    for (int dj = -1; dj <= 1; dj++) {
      int w2 = wx + dj;
      if (w2 < 0 || w2 >= W) continue;
      s += xb[(size_t)h2 * W + w2] * wc[(di + 1) * 3 + (dj + 1)];
    }
  }
  if (residual) s += xb[(size_t)hy * W + wx];
  y[i] = s;
}

// ---------------------------------------------------------------------------
// Depthwise 3x3 vectorized fp32 (x -> xp), 4 pixels/thread, W%4==0.
// ---------------------------------------------------------------------------
__global__ void dwconv4_kernel(const float* __restrict__ x, const float* __restrict__ w,
                               const float* __restrict__ bias, float* __restrict__ y,
                               int C, int H, int W, int total4, int residual) {
  int i = blockIdx.x * 256 + threadIdx.x;
  if (i >= total4) return;
  int W4 = W >> 2;
  int wq = (i % W4) * 4;
  int t = i / W4;
  int hy = t % H;
  int bc = t / H;
  int c = bc % C;
  const float* xb = x + (size_t)bc * H * W;
  const float* wc = w + c * 9;
  float bv = bias ? bias[c] : 0.0f;
  float s0 = bv, s1 = bv, s2 = bv, s3 = bv;
  for (int di = -1; di <= 1; di++) {
    int h2 = hy + di;
    if (h2 < 0 || h2 >= H) continue;
    const float* row = xb + (size_t)h2 * W + wq;
    float4 cv = *(const float4*)row;
    float lf = (wq > 0) ? row[-1] : 0.0f;
    float rt = (wq + 4 < W) ? row[4] : 0.0f;
    float w0 = wc[(di + 1) * 3 + 0];
    float w1 = wc[(di + 1) * 3 + 1];
    float w2 = wc[(di + 1) * 3 + 2];
    s0 += w0 * lf   + w1 * cv.x + w2 * cv.y;
    s1 += w0 * cv.x + w1 * cv.y + w2 * cv.z;
    s2 += w0 * cv.y + w1 * cv.z + w2 * cv.w;
    s3 += w0 * cv.z + w1 * cv.w + w2 * rt;
  }
  if (residual) {
    float4 cc = *(const float4*)(xb + (size_t)hy * W + wq);
    s0 += cc.x; s1 += cc.y; s2 += cc.z; s3 += cc.w;
  }
  *(float4*)(y + (size_t)bc * H * W + (size_t)hy * W + wq) = make_float4(s0, s1, s2, s3);
}

// ---------------------------------------------------------------------------
// Depthwise 3x3 for the q path: fp32 NCHW in -> bf16 NHWC out, pre-scaled
// by 32^-0.5 (folded attention scale).
// ---------------------------------------------------------------------------
__global__ void dwconv_q_kernel(const float* __restrict__ x, const float* __restrict__ w,
                                unsigned short* __restrict__ qn, int total) {
  int i = blockIdx.x * 256 + threadIdx.x;
  if (i >= total) return;
  int wx = i % HS;
  int t = i / HS;
  int hy = t % HS;
  int bc = t / HS;
  int c = bc & 127;
  int b = bc >> 7;
  const float* xb = x + (size_t)bc * HSW;
  const float* wc = w + c * 9;
  float s = 0.0f;
  for (int di = -1; di <= 1; di++) {
    int h2 = hy + di;
    if (h2 < 0 || h2 >= HS) continue;
    for (int dj = -1; dj <= 1; dj++) {
      int w2 = wx + dj;
      if (w2 < 0 || w2 >= HS) continue;
      s += xb[(size_t)h2 * HS + w2] * wc[(di + 1) * 3 + (dj + 1)];
    }
  }
  qn[((size_t)(b * HSW + hy * HS + wx)) * 128 + c] = f2bf(s * 0.17677669529663688f);
}

// ---------------------------------------------------------------------------
// Depthwise 3x3 kv path: fp32 NCHW (256ch) in -> K half (c<128) bf16 NHWC,
// V half (c>=128) bf16 NCHW. 4 pixels/thread.
// ---------------------------------------------------------------------------
__global__ void dwconv_kv_kernel(const float* __restrict__ x, const float* __restrict__ w,
                                 unsigned short* __restrict__ kT, unsigned short* __restrict__ v,
                                 int total4) {
  int i = blockIdx.x * 256 + threadIdx.x;
  if (i >= total4) return;
  int W4 = HX >> 2;
  int wq = (i % W4) * 4;
  int t = i / W4;
  int hy = t % HX;
  int bc = t / HX;
  int c = bc & 255;
  int b = bc >> 8;
  const float* xb = x + (size_t)bc * HXW;
  const float* wc = w + c * 9;
  float s0 = 0, s1 = 0, s2 = 0, s3 = 0;
  for (int di = -1; di <= 1; di++) {
    int h2 = hy + di;
    if (h2 < 0 || h2 >= HX) continue;
    const float* row = xb + (size_t)h2 * HX + wq;
    float4 cv = *(const float4*)row;
    float lf = (wq > 0) ? row[-1] : 0.0f;
    float rt = (wq + 4 < HX) ? row[4] : 0.0f;
    float w0 = wc[(di + 1) * 3 + 0];
    float w1 = wc[(di + 1) * 3 + 1];
    float w2 = wc[(di + 1) * 3 + 2];
    s0 += w0 * lf   + w1 * cv.x + w2 * cv.y;
    s1 += w0 * cv.x + w1 * cv.y + w2 * cv.z;
    s2 += w0 * cv.y + w1 * cv.z + w2 * cv.w;
    s3 += w0 * cv.z + w1 * cv.w + w2 * rt;
  }
  if (c < 128) {
    size_t base = ((size_t)(b * HXW) + hy * HX + wq) * 128 + c;
    kT[base]       = f2bf(s0);
    kT[base + 128] = f2bf(s1);
    kT[base + 256] = f2bf(s2);
    kT[base + 384] = f2bf(s3);
  } else {
    uint2 d;
    d.x = (uint32_t)f2bf(s0) | ((uint32_t)f2bf(s1) << 16);
    d.y = (uint32_t)f2bf(s2) | ((uint32_t)f2bf(s3) << 16);
    *(uint2*)(v + ((size_t)(b * 128 + (c - 128))) * HXW + (size_t)hy * HX + wq) = d;
  }
}

// ---------------------------------------------------------------------------
// 1x1 conv tiled SGEMM (fp32), unchanged from round 2.
// ---------------------------------------------------------------------------
template <int O>
__global__ __launch_bounds__(256) void conv1_kernel(const float* __restrict__ x,
                                                    const float* __restrict__ w,
                                                    float* __restrict__ y, int HW) {
  constexpr int K = 128;
  constexpr int BK = 32;
  __shared__ __align__(16) float ws_s[BK][64];
  __shared__ __align__(16) float xs_s[BK][64];
  int b = blockIdx.z;
  int o0 = blockIdx.y * 64;
  int p0 = blockIdx.x * 64;
  const float* xb = x + (size_t)b * K * HW;
  int tx = threadIdx.x & 15;
  int ty = threadIdx.x >> 4;
  float acc[4][4] = {};
  int lo = threadIdx.x >> 2;
  int lk = (threadIdx.x & 3) * 8;
  int lc = threadIdx.x >> 3;
  int lp = (threadIdx.x & 7) * 8;

  for (int k0 = 0; k0 < K; k0 += BK) {
    __syncthreads();
    {
      const float* wp = w + (size_t)(o0 + lo) * K + k0 + lk;
      float4 a = *(const float4*)wp;
      float4 bq = *(const float4*)(wp + 4);
      ws_s[lk + 0][lo] = a.x;  ws_s[lk + 1][lo] = a.y;
      ws_s[lk + 2][lo] = a.z;  ws_s[lk + 3][lo] = a.w;
      ws_s[lk + 4][lo] = bq.x; ws_s[lk + 5][lo] = bq.y;
      ws_s[lk + 6][lo] = bq.z; ws_s[lk + 7][lo] = bq.w;
    }
    {
      int p = p0 + lp;
      const float* xp = xb + (size_t)(k0 + lc) * HW;
      float4 a, bq;
      if (p + 7 < HW) {
        a = *(const float4*)(xp + p);
        bq = *(const float4*)(xp + p + 4);
      } else {
        float tv[8];
#pragma unroll
        for (int j = 0; j < 8; j++) tv[j] = (p + j < HW) ? xp[p + j] : 0.0f;
        a = make_float4(tv[0], tv[1], tv[2], tv[3]);
        bq = make_float4(tv[4], tv[5], tv[6], tv[7]);
      }
      *(float4*)&xs_s[lc][lp] = a;
      *(float4*)&xs_s[lc][lp + 4] = bq;
    }
    __syncthreads();
#pragma unroll
    for (int k = 0; k < BK; k++) {
      float4 wv = *(const float4*)&ws_s[k][ty * 4];
      float4 xv = *(const float4*)&xs_s[k][tx * 4];
      acc[0][0] += wv.x * xv.x; acc[0][1] += wv.x * xv.y; acc[0][2] += wv.x * xv.z; acc[0][3] += wv.x * xv.w;
      acc[1][0] += wv.y * xv.x; acc[1][1] += wv.y * xv.y; acc[1][2] += wv.y * xv.z; acc[1][3] += wv.y * xv.w;
      acc[2][0] += wv.z * xv.x; acc[2][1] += wv.z * xv.y; acc[2][2] += wv.z * xv.z; acc[2][3] += wv.z * xv.w;
      acc[3][0] += wv.w * xv.x; acc[3][1] += wv.w * xv.y; acc[3][2] += wv.w * xv.z; acc[3][3] += wv.w * xv.w;
    }
  }
  int p = p0 + tx * 4;
  float* yb = y + (size_t)b * O * HW + (size_t)(o0 + ty * 4) * HW;
#pragma unroll
  for (int j = 0; j < 4; j++) {
    float* yr = yb + (size_t)j * HW + p;
    if (p + 3 < HW) {
      *(float4*)yr = make_float4(acc[j][0], acc[j][1], acc[j][2], acc[j][3]);
    } else {
#pragma unroll
      for (int e = 0; e < 4; e++) if (p + e < HW) yr[e] = acc[j][e];
    }
  }
}

// ---------------------------------------------------------------------------
// MFMA windowed attention. Block = (window n, head h, batch b), 4 waves.
// Wave w handles window rows 8w..8w+7 (32 keys/chunk = one window row).
//  S^T = K·Q^T   (A = K [key][ch] from NHWC kT, B = Q^T from NHWC qn regs)
//  softmax on S^T: query = lane&15 (col), keys in quads/regs -> 2 shuffles
//  O^T = V^T·P^T (A = V^T [ch][key] from NCHW v, B = P via LDS round-trip)
// Flash merge of 4 waves at the end. out: (2,100,128,64) fp32.
// ---------------------------------------------------------------------------
__global__ __launch_bounds__(256) void attn_mfma_kernel(
    const unsigned short* __restrict__ qn,   // (2,62,62,128) bf16, pre-scaled
    const unsigned short* __restrict__ kT,   // (2,248,248,128) bf16 NHWC
    const unsigned short* __restrict__ vp,   // (2,128,248,248) bf16 NCHW
    float* __restrict__ o) {
  int n = blockIdx.x, h = blockIdx.y, b = blockIdx.z;
  int wi = n / 10, wj = n % 10;
  int wave = threadIdx.x >> 6;
  int lane = threadIdx.x & 63;
  int quad = lane >> 4;
  int l15 = lane & 15;
  int y0 = 24 * wi, x0 = 24 * wj;

  __shared__ __align__(16) unsigned short lds[18432];  // 36,864 B
  unsigned short* Kw = lds + wave * 1024;          // [pix][32ch]  2KB
  unsigned short* Vw = lds + 4096 + wave * 1024;   // [ch][32pix]  2KB
  unsigned short* Pw = lds + 8192 + wave * 2560;   // [q][40keys]  5KB

  // Q B-fragments, once per block (held in registers)
  bf16x8 QB[4];
#pragma unroll
  for (int nt = 0; nt < 4; nt++) {
    int qq = nt * 16 + l15;
    int qy = 6 * wi + (qq >> 3), qx = 6 * wj + (qq & 7);
    QB[nt] = __builtin_bit_cast(bf16x8,
        *(const uint4*)(qn + ((size_t)(b * HSW + qy * HS + qx)) * 128 + h * 32 + quad * 8));
  }

  f32x4 Oacc[2][4];
#pragma unroll
  for (int a = 0; a < 2; a++)
#pragma unroll
    for (int c = 0; c < 4; c++) Oacc[a][c] = f32x4{0.f, 0.f, 0.f, 0.f};
  float m[4] = {-1e30f, -1e30f, -1e30f, -1e30f};
  float l[4] = {0.f, 0.f, 0.f, 0.f};

  const unsigned short* kb = kT + (size_t)b * HXW * 128;
  const unsigned short* vb = vp + (size_t)b * 128 * HXW + (size_t)(h * 32) * HXW;

  auto loadrow = [&](int r, uint4* krr, uint4* vrr) {
#pragma unroll
    for (int t = 0; t < 2; t++) {
      int idx = t * 64 + lane;
      int e = idx >> 2, prt = idx & 3;  // e = pixel (K) or channel (V)
      int y = y0 + r;
      krr[t] = *(const uint4*)(kb + ((size_t)(y * HX + x0 + e)) * 128 + h * 32 + prt * 8);
      vrr[t] = *(const uint4*)(vb + (size_t)e * HXW + (size_t)y * HX + x0 + prt * 8);
    }
  };

  uint4 kr[2], vr[2];
  loadrow(wave * 8, kr, vr);
  const f32x4 zf = {0.f, 0.f, 0.f, 0.f};

#pragma unroll 1
  for (int r8 = 0; r8 < 8; r8++) {
    ((uint4*)Kw)[lane] = kr[0];
    ((uint4*)Kw)[64 + lane] = kr[1];
    ((uint4*)Vw)[lane] = vr[0];
    ((uint4*)Vw)[64 + lane] = vr[1];
    uint4 kr2[2], vr2[2];
    if (r8 < 7) loadrow(wave * 8 + r8 + 1, kr2, vr2);

    bf16x8 KA[2], VA[2];
#pragma unroll
    for (int mt = 0; mt < 2; mt++) {
      KA[mt] = __builtin_bit_cast(bf16x8, ((const uint4*)Kw)[(16 * mt + l15) * 4 + quad]);
      VA[mt] = __builtin_bit_cast(bf16x8, ((const uint4*)Vw)[(16 * mt + l15) * 4 + quad]);
    }

    f32x4 S[2][4];
#pragma unroll
    for (int mt = 0; mt < 2; mt++)
#pragma unroll
      for (int nt = 0; nt < 4; nt++)
        S[mt][nt] = __builtin_amdgcn_mfma_f32_16x16x32_bf16(KA[mt], QB[nt], zf, 0, 0, 0);

#pragma unroll
    for (int nt = 0; nt < 4; nt++) {
      float cmax = S[0][nt][0];
#pragma unroll
      for (int r = 1; r < 4; r++) cmax = fmaxf(cmax, S[0][nt][r]);
#pragma unroll
      for (int r = 0; r < 4; r++) cmax = fmaxf(cmax, S[1][nt][r]);
      cmax = fmaxf(cmax, __shfl_xor(cmax, 16, 64));
      cmax = fmaxf(cmax, __shfl_xor(cmax, 32, 64));
      float mn = fmaxf(m[nt], cmax);
      float al = __expf(m[nt] - mn);
      m[nt] = mn;
      float pv[2][4];
      float cs = 0.f;
#pragma unroll
      for (int mt = 0; mt < 2; mt++)
#pragma unroll
        for (int r = 0; r < 4; r++) {
          pv[mt][r] = __expf(S[mt][nt][r] - mn);
          cs += pv[mt][r];
        }
      cs += __shfl_xor(cs, 16, 64);
      cs += __shfl_xor(cs, 32, 64);
      l[nt] = l[nt] * al + cs;
#pragma unroll
      for (int mt = 0; mt < 2; mt++)
#pragma unroll
        for (int r = 0; r < 4; r++) Oacc[mt][nt][r] *= al;
#pragma unroll
      for (int mt = 0; mt < 2; mt++) {
        uint2 d;
        d.x = (uint32_t)f2bf(pv[mt][0]) | ((uint32_t)f2bf(pv[mt][1]) << 16);
        d.y = (uint32_t)f2bf(pv[mt][2]) | ((uint32_t)f2bf(pv[mt][3]) << 16);
        *(uint2*)(Pw + (16 * nt + l15) * 40 + 16 * mt + quad * 4) = d;
      }
    }
#pragma unroll
    for (int nt = 0; nt < 4; nt++) {
      bf16x8 PB = __builtin_bit_cast(bf16x8, *(const uint4*)(Pw + (16 * nt + l15) * 40 + quad * 8));
      Oacc[0][nt] = __builtin_amdgcn_mfma_f32_16x16x32_bf16(VA[0], PB, Oacc[0][nt], 0, 0, 0);
      Oacc[1][nt] = __builtin_amdgcn_mfma_f32_16x16x32_bf16(VA[1], PB, Oacc[1][nt], 0, 0, 0);
    }
    if (r8 < 7) {
      kr[0] = kr2[0]; kr[1] = kr2[1];
      vr[0] = vr2[0]; vr[1] = vr2[1];
    }
  }

  // ---- merge the 4 waves (flash combine) ----
  __syncthreads();
  float* mO = (float*)lds;                 // [w][32ch][64q]  32 KB
  float* mM = (float*)(lds + 16384);       // [w][64q]
  float* mL = mM + 256;                    // [w][64q]
#pragma unroll
  for (int mt = 0; mt < 2; mt++)
#pragma unroll
    for (int nt = 0; nt < 4; nt++)
#pragma unroll
      for (int r = 0; r < 4; r++)
        mO[wave * 2048 + (16 * mt + quad * 4 + r) * 64 + 16 * nt + l15] = Oacc[mt][nt][r];
  if (quad == 0) {
#pragma unroll
    for (int nt = 0; nt < 4; nt++) {
      mM[wave * 64 + 16 * nt + l15] = m[nt];
      mL[wave * 64 + 16 * nt + l15] = l[nt];
    }
  }
  __syncthreads();
  {
    int q = threadIdx.x & 63;
    int chg = (threadIdx.x >> 6) * 8;
    float m0 = mM[q], m1 = mM[64 + q], m2 = mM[128 + q], m3 = mM[192 + q];
    float mm = fmaxf(fmaxf(m0, m1), fmaxf(m2, m3));
    float e0 = __expf(m0 - mm), e1 = __expf(m1 - mm);
    float e2 = __expf(m2 - mm), e3 = __expf(m3 - mm);
    float lsum = mL[q] * e0 + mL[64 + q] * e1 + mL[128 + q] * e2 + mL[192 + q] * e3;
    float inv = 1.0f / lsum;
    float* ob = o + (((size_t)(b * 100 + n)) * 128 + h * 32 + chg) * 64 + q;
#pragma unroll
    for (int e = 0; e < 8; e++) {
      int ch = chg + e;
      float s = mO[ch * 64 + q] * e0 + mO[2048 + ch * 64 + q] * e1 +
                mO[4096 + ch * 64 + q] * e2 + mO[6144 + ch * 64 + q] * e3;
      ob[(size_t)e * 64] = s * inv;
    }
  }
}

// ---------------------------------------------------------------------------
// Reverse: scatter-average overlapping 8x8 windows (step 6) into (2,128,62,62)
// ---------------------------------------------------------------------------
__global__ void reverse_kernel(const float* __restrict__ win, float* __restrict__ out) {
  int i = blockIdx.x * 256 + threadIdx.x;
  const int total = 2 * 128 * HSW;
  if (i >= total) return;
  int x = i % HS;
  int t = i / HS;
  int y = t % HS;
  t /= HS;
  int c = t % 128;
  int b = t / 128;
  int wi0 = (y >= 7) ? (y - 2) / 6 : 0;
  int wi1 = min(9, y / 6);
  int wj0 = (x >= 7) ? (x - 2) / 6 : 0;
  int wj1 = min(9, x / 6);
  float s = 0.0f;
  for (int wi = wi0; wi <= wi1; wi++)
    for (int wj = wj0; wj <= wj1; wj++) {
      int di = y - 6 * wi, dj = x - 6 * wj;
      s += win[(((size_t)(b * 100 + wi * 10 + wj)) * 128 + c) * 64 + di * 8 + dj];
    }
  float cnt = (float)((wi1 - wi0 + 1) * (wj1 - wj0 + 1));
  out[i] = s / cnt;
}

// ---------------------------------------------------------------------------
extern "C" void kernel_launch(void* const* d_in, const int* in_sizes, int n_in,
                              void* d_out, int out_size, void* d_ws, size_t ws_size,
                              hipStream_t stream) {
  const float* x      = (const float*)d_in[0];
  const float* sp     = (const float*)d_in[1];
  const float* w_pos  = (const float*)d_in[2];
  const float* b_pos  = (const float*)d_in[3];
  const float* w_q    = (const float*)d_in[4];
  const float* w_qdw  = (const float*)d_in[5];
  const float* w_kv   = (const float*)d_in[6];
  const float* w_kvdw = (const float*)d_in[7];
  const float* w_out  = (const float*)d_in[8];
  float* out = (float*)d_out;

  const size_t N_x   = (size_t)2 * 128 * HXW;  // 15,745,024 floats
  const size_t N_t   = (size_t)2 * 256 * HXW;  // 31,490,048 floats
  const size_t N_s   = (size_t)2 * 128 * HSW;  //    984,064 floats
  const size_t N_att = (size_t)2 * 100 * 128 * 64;

  float* ws = (float*)d_ws;
  // bf16 K (NHWC) + V (NCHW) exactly fill the xp region (aliased; xp dead first)
  unsigned short* kT = (unsigned short*)ws;           // 2*HXW*128 ushorts
  unsigned short* vv = kT + (size_t)2 * HXW * 128;    // 2*HXW*128 ushorts
  float* xp  = ws;
  float* tkv = ws + N_x;
  float* att = tkv;            // alias: tkv dead after dwconv_kv
  float* rev = tkv + N_att;
  float* spp = ws + N_x + N_t;
  float* tq  = spp + N_s;
  unsigned short* qn = (unsigned short*)(tq + N_s);   // N_s ushorts
  (void)ws_size; (void)in_sizes; (void)n_in; (void)out_size;

  // 1. xp = x + dwconv3(x, w_pos, b_pos)
  {
    int total4 = (int)(N_x / 4);
    dwconv4_kernel<<<(total4 + 255) / 256, 256, 0, stream>>>(x, w_pos, b_pos, xp, 128, HX, HX, total4, 1);
  }
  // 2. spp = sp + dwconv3(sp, w_pos, b_pos)
  {
    int total = (int)N_s;
    dwconv3_kernel<<<(total + 255) / 256, 256, 0, stream>>>(sp, w_pos, b_pos, spp, 128, HS, HS, total, 1);
  }
  // 3. tq = conv1(spp, w_q)
  {
    int HW = HSW;
    dim3 grid((HW + 63) / 64, 2, 2);
    conv1_kernel<128><<<grid, 256, 0, stream>>>(spp, w_q, tq, HW);
  }
  // 4. qn = bf16_nhwc(dwconv3(tq, w_qdw)) * 32^-0.5
  {
    int total = (int)N_s;
    dwconv_q_kernel<<<(total + 255) / 256, 256, 0, stream>>>(tq, w_qdw, qn, total);
  }
  // 5. tkv = conv1(xp, w_kv)   (O=256)
  {
    int HW = HXW;
    dim3 grid((HW + 63) / 64, 4, 2);
    conv1_kernel<256><<<grid, 256, 0, stream>>>(xp, w_kv, tkv, HW);
  }
  // 6. kT/vv = bf16(dwconv3(tkv, w_kvdw))   (overwrites xp region; xp dead)
  {
    int total4 = (int)(N_t / 4);
    dwconv_kv_kernel<<<(total4 + 255) / 256, 256, 0, stream>>>(tkv, w_kvdw, kT, vv, total4);
  }
  // 7. attention -> att (2,100,128,64)   (att aliases tkv; tkv dead)
  {
    dim3 grid(100, 4, 2);
    attn_mfma_kernel<<<grid, 256, 0, stream>>>(qn, kT, vv, att);
  }
  // 8. rev = reverse(att)
  {
    int total = (int)N_s;
    reverse_kernel<<<(total + 255) / 256, 256, 0, stream>>>(att, rev);
  }
  // 9. out = conv1(rev, w_out)
  {
    int HW = HSW;
    dim3 grid((HW + 63) / 64, 2, 2);
    conv1_kernel<128><<<grid, 256, 0, stream>>>(rev, w_out, out, HW);
  }
}